// Round 1
// baseline (594.197 us; speedup 1.0000x reference)
//
#include <hip/hip_runtime.h>
#include <math.h>

namespace {

constexpr int HDIM = 64;
constexpr int WDIM = 64;
constexpr int HW = HDIM * WDIM;   // 4096
constexpr int C = 512;
constexpr int G = 4;
constexpr int CG = 128;
constexpr int K = 9;
constexpr int NH = 8;
constexpr int DH = 64;
constexpr float SCALE = 0.125f;   // DH^-0.5

// ---------- transpose x (C, HW) -> xt (HW, C) ----------
__global__ void k_transpose(const float* __restrict__ x, float* __restrict__ xt) {
  __shared__ float tile[32][33];
  int p0 = blockIdx.x * 32;
  int c0 = blockIdx.y * 32;
  int tx = threadIdx.x;
  int ty = threadIdx.y;
  for (int r = ty; r < 32; r += 8)
    tile[r][tx] = x[(c0 + r) * HW + p0 + tx];
  __syncthreads();
  for (int r = ty; r < 32; r += 8)
    xt[(p0 + r) * C + c0 + tx] = tile[tx][r];
}

// ---------- generic NN GEMM: Cm[m][n] = sum_k A[m][k]*B[k][n] + bias[m] ----------
__global__ void k_gemm_nn(const float* __restrict__ A, const float* __restrict__ B,
                          const float* __restrict__ bias, float* __restrict__ Cm,
                          int M, int N, int Kd) {
  __shared__ float As[16][64];
  __shared__ float Bs[16][64];
  int bm = blockIdx.y * 64, bn = blockIdx.x * 64;
  int t = threadIdx.x;
  int tm = (t >> 4) << 2;
  int tn = (t & 15) << 2;
  int ra = t >> 2;
  int ka = (t & 3) << 2;
  int kb = t >> 4;
  int nb = (t & 15) << 2;
  float acc[4][4] = {};
  for (int k0 = 0; k0 < Kd; k0 += 16) {
    float4 a4 = *(const float4*)&A[(bm + ra) * Kd + k0 + ka];
    float4 b4 = *(const float4*)&B[(k0 + kb) * N + bn + nb];
    __syncthreads();
    As[ka + 0][ra] = a4.x;
    As[ka + 1][ra] = a4.y;
    As[ka + 2][ra] = a4.z;
    As[ka + 3][ra] = a4.w;
    *(float4*)&Bs[kb][nb] = b4;
    __syncthreads();
#pragma unroll
    for (int kk = 0; kk < 16; ++kk) {
      float av[4], bw[4];
#pragma unroll
      for (int a = 0; a < 4; ++a) av[a] = As[kk][tm + a];
#pragma unroll
      for (int b = 0; b < 4; ++b) bw[b] = Bs[kk][tn + b];
#pragma unroll
      for (int a = 0; a < 4; ++a)
#pragma unroll
        for (int b = 0; b < 4; ++b) acc[a][b] += av[a] * bw[b];
    }
  }
#pragma unroll
  for (int a = 0; a < 4; ++a) {
    float bb = bias[bm + tm + a];
    float4 o;
    o.x = acc[a][0] + bb; o.y = acc[a][1] + bb; o.z = acc[a][2] + bb; o.w = acc[a][3] + bb;
    *(float4*)&Cm[(bm + tm + a) * N + bn + tn] = o;
  }
}

// ---------- gather q at selected points: qsel[c][i] ----------
__global__ void k_qsel(const float* __restrict__ q, const int* __restrict__ idx,
                       float* __restrict__ qsel, int n) {
  int i = blockIdx.x * 256 + threadIdx.x;
  int c = blockIdx.y;
  if (i >= n) return;
  int p = idx[2 * i] * WDIM + idx[2 * i + 1];
  qsel[c * n + i] = q[c * HW + p];
}

// ---------- qk2[i][h*512+c'] = sum_d qsel[h*64+d][i] * wk[h*64+d][c'] ----------
__global__ void k_qk(const float* __restrict__ qsel, const float* __restrict__ wk,
                     float* __restrict__ qk2, int n) {
  __shared__ float As[64][65];  // As[d][ii]
  __shared__ float Bs[64][65];  // Bs[d][cc]
  int i0 = blockIdx.x * 64;
  int c0 = blockIdx.y * 64;
  int h = blockIdx.z;
  int t = threadIdx.x;
  for (int j = t; j < 4096; j += 256) {
    int d = j >> 6, ii = j & 63;
    As[d][ii] = qsel[(h * 64 + d) * n + i0 + ii];
    Bs[d][ii] = wk[(h * 64 + d) * C + c0 + ii];
  }
  __syncthreads();
  int tm = (t >> 4) << 2;
  int tn = (t & 15) << 2;
  float acc[4][4] = {};
#pragma unroll 4
  for (int d = 0; d < 64; ++d) {
    float av[4], bw[4];
#pragma unroll
    for (int a = 0; a < 4; ++a) av[a] = As[d][tm + a];
#pragma unroll
    for (int b = 0; b < 4; ++b) bw[b] = Bs[d][tn + b];
#pragma unroll
    for (int a = 0; a < 4; ++a)
#pragma unroll
      for (int b = 0; b < 4; ++b) acc[a][b] += av[a] * bw[b];
  }
#pragma unroll
  for (int a = 0; a < 4; ++a) {
    float4 o = {acc[a][0], acc[a][1], acc[a][2], acc[a][3]};
    *(float4*)&qk2[(size_t)(i0 + tm + a) * (NH * C) + h * C + c0 + tn] = o;
  }
}

// ---------- depthwise 3x3 conv + LayerNorm(channel) + exact GELU ----------
__global__ void k_dwln(const float* __restrict__ in, const float* __restrict__ w9,
                       const float* __restrict__ wb, const float* __restrict__ lng,
                       const float* __restrict__ lnb, float* __restrict__ outp) {
  int g = blockIdx.x >> 6;
  int h = blockIdx.x & 63;
  int t = threadIdx.x;
  int cg = t & 127;
  int grp = t >> 7;     // two w-positions processed concurrently
  int c = g * CG + cg;
  const float* base = in + c * HW;
  float wreg[9];
#pragma unroll
  for (int j = 0; j < 9; ++j) wreg[j] = w9[cg * 9 + j];
  float wbv = wb[cg], gv = lng[cg], bbv = lnb[cg];
  __shared__ float red[2][2][2];
  int wave = (t >> 6) & 1;
  for (int w = grp; w < 64; w += 2) {
    float acc = wbv;
#pragma unroll
    for (int dy = 0; dy < 3; ++dy) {
      int hh = h + dy - 1;
      if (hh < 0 || hh >= HDIM) continue;
#pragma unroll
      for (int dx = 0; dx < 3; ++dx) {
        int ww = w + dx - 1;
        if (ww < 0 || ww >= WDIM) continue;
        acc += wreg[dy * 3 + dx] * base[hh * WDIM + ww];
      }
    }
    float s = acc, s2 = acc * acc;
#pragma unroll
    for (int o = 32; o > 0; o >>= 1) {
      s += __shfl_xor(s, o, 64);
      s2 += __shfl_xor(s2, o, 64);
    }
    if ((t & 63) == 0) {
      red[grp][wave][0] = s;
      red[grp][wave][1] = s2;
    }
    __syncthreads();
    float mean = (red[grp][0][0] + red[grp][1][0]) * (1.0f / 128.0f);
    float var = (red[grp][0][1] + red[grp][1][1]) * (1.0f / 128.0f) - mean * mean;
    float rstd = rsqrtf(var + 1e-5f);
    float xn = (acc - mean) * rstd * gv + bbv;
    float ge = 0.5f * xn * (1.0f + erff(xn * 0.70710678f));
    outp[c * HW + h * WDIM + w] = ge;
    __syncthreads();
  }
}

// ---------- offset projection + tanh + sampling positions (selected pts only) ----------
__global__ void k_offsets(const float* __restrict__ t2, const float* __restrict__ ow3,
                          const int* __restrict__ idx, float* __restrict__ pos, int n) {
  int i = blockIdx.x >> 2;
  int g = blockIdx.x & 3;
  int l = threadIdx.x;
  int iy = idx[2 * i], ix = idx[2 * i + 1];
  int p = iy * WDIM + ix;
  __shared__ float tl[128];
  __shared__ float ov[18];
  tl[l] = t2[(g * CG + l) * HW + p];
  tl[l + 64] = t2[(g * CG + l + 64) * HW + p];
  __syncthreads();
  if (l < 18) {
    float a = 0.0f;
    for (int j = 0; j < 128; ++j) a += ow3[l * CG + j] * tl[j];
    ov[l] = a;
  }
  __syncthreads();
  if (l < 9) {
    int dy = l / 3, dx = l % 3;
    int ryi = min(max(iy + dy - 1, 0), HDIM - 1);
    int rxi = min(max(ix + dx - 1, 0), WDIM - 1);
    float ry = (ryi + 0.5f) * (2.0f / HDIM) - 1.0f;
    float rx = (rxi + 0.5f) * (2.0f / WDIM) - 1.0f;
    float py = tanhf(ov[2 * l]) * (2.0f / HDIM) + ry;      // tanh * (1/H) * FACTOR
    float px = tanhf(ov[2 * l + 1]) * (2.0f / WDIM) + rx;
    int o = ((i * G + g) * K + l) * 2;
    pos[o] = py;
    pos[o + 1] = px;
  }
}

// ---------- bilinear sampler: writes xr_sel (all C) and xs_sel (own-group C) ----------
__global__ void k_sample(const float* __restrict__ xt, const float* __restrict__ pos,
                         float* __restrict__ xr, float* __restrict__ xs2, int n) {
  int i = blockIdx.x >> 2;
  int g = blockIdx.x & 3;
  int t = threadIdx.x;
#pragma unroll 1
  for (int kk = 0; kk < K; ++kk) {
    int o = ((i * G + g) * K + kk) * 2;
    float py = pos[o], px = pos[o + 1];
    float gx = (px + 1.0f) * 0.5f * (WDIM - 1);
    float gy = (py + 1.0f) * 0.5f * (HDIM - 1);
    float x0f = floorf(gx), y0f = floorf(gy);
    float wx1 = gx - x0f, wx0 = 1.0f - wx1;
    float wy1 = gy - y0f, wy0 = 1.0f - wy1;
    int x0 = (int)x0f, y0 = (int)y0f;
    int x1 = x0 + 1, y1 = y0 + 1;
    bool vx0 = (x0 >= 0) && (x0 < WDIM);
    bool vx1 = (x1 >= 0) && (x1 < WDIM);
    bool vy0 = (y0 >= 0) && (y0 < HDIM);
    bool vy1 = (y1 >= 0) && (y1 < HDIM);
    float w00 = (vy0 && vx0) ? wy0 * wx0 : 0.0f;
    float w01 = (vy0 && vx1) ? wy0 * wx1 : 0.0f;
    float w10 = (vy1 && vx0) ? wy1 * wx0 : 0.0f;
    float w11 = (vy1 && vx1) ? wy1 * wx1 : 0.0f;
    int x0c = min(max(x0, 0), WDIM - 1), x1c = min(max(x1, 0), WDIM - 1);
    int y0c = min(max(y0, 0), HDIM - 1), y1c = min(max(y1, 0), HDIM - 1);
    const float* p00 = xt + (y0c * WDIM + x0c) * C;
    const float* p01 = xt + (y0c * WDIM + x1c) * C;
    const float* p10 = xt + (y1c * WDIM + x0c) * C;
    const float* p11 = xt + (y1c * WDIM + x1c) * C;
    size_t rbase = ((size_t)i * (G * K) + g * K + kk) * C;
    size_t sbase = ((size_t)i * K + kk) * C;
    for (int c = t; c < C; c += 256) {
      float v = w00 * p00[c] + w01 * p01[c] + w10 * p10[c] + w11 * p11[c];
      xr[rbase + c] = v;
      if ((c >> 7) == g) xs2[sbase + c] = v;
    }
  }
}

// ---------- fused per-point attention: logits -> softmax -> z ----------
__global__ void __launch_bounds__(256)
k_attn(const float* __restrict__ qk2, const float* __restrict__ xs2,
       float* __restrict__ attn_out, float* __restrict__ z2, int n) {
  int i = blockIdx.x;
  int t = threadIdx.x;
  __shared__ float qkl[NH * C];  // 4096
  __shared__ float xsl[K * C];   // 4608
  __shared__ float lg[NH][K];
  __shared__ float pr[NH][K];
  for (int j = t; j < NH * C; j += 256) qkl[j] = qk2[(size_t)i * (NH * C) + j];
  for (int j = t; j < K * C; j += 256) xsl[j] = xs2[(size_t)i * (K * C) + j];
  __syncthreads();
  int wave = t >> 6, lane = t & 63;
#pragma unroll
  for (int hh = 0; hh < 2; ++hh) {
    int h = wave * 2 + hh;
#pragma unroll 1
    for (int kk = 0; kk < K; ++kk) {
      float s = 0.0f;
#pragma unroll
      for (int m = 0; m < 8; ++m)
        s += qkl[h * C + lane + 64 * m] * xsl[kk * C + lane + 64 * m];
#pragma unroll
      for (int o = 32; o > 0; o >>= 1) s += __shfl_xor(s, o, 64);
      if (lane == 0) lg[h][kk] = s * SCALE;
    }
  }
  __syncthreads();
  if (t < NH) {
    float mx = -1e30f;
    for (int kk = 0; kk < K; ++kk) mx = fmaxf(mx, lg[t][kk]);
    float sm = 0.0f;
    float e[K];
    for (int kk = 0; kk < K; ++kk) { e[kk] = expf(lg[t][kk] - mx); sm += e[kk]; }
    float inv = 1.0f / sm;
    for (int kk = 0; kk < K; ++kk) {
      float p = e[kk] * inv;
      pr[t][kk] = p;
      attn_out[((size_t)t * n + i) * K + kk] = p;
    }
  }
  __syncthreads();
  for (int j = t; j < NH * C; j += 256) {
    int h = j >> 9;
    int cc = j & 511;
    float a = 0.0f;
#pragma unroll
    for (int kk = 0; kk < K; ++kk) a += pr[h][kk] * xsl[kk * C + cc];
    z2[(size_t)i * (NH * C) + j] = a;
  }
}

// ---------- out[c][i] = sum_c' wv[c][c'] * z2[i][h*512+c'] + bv[c]  (c = h*64+d) ----------
__global__ void k_outgemm(const float* __restrict__ wv, const float* __restrict__ z2,
                          const float* __restrict__ bv, float* __restrict__ outb, int n) {
  __shared__ float As[16][64];  // As[kk][d]
  __shared__ float Bs[16][68];  // Bs[kk][ii]
  int i0 = blockIdx.x * 64;
  int h = blockIdx.y;
  int t = threadIdx.x;
  int tm = (t >> 4) << 2, tn = (t & 15) << 2;
  int ra = t >> 2, ka = (t & 3) << 2;
  int ib = t & 63, kq = (t >> 6) << 2;
  float acc[4][4] = {};
  for (int k0 = 0; k0 < C; k0 += 16) {
    float4 a4 = *(const float4*)&wv[(h * DH + ra) * C + k0 + ka];
    float4 b4 = *(const float4*)&z2[(size_t)(i0 + ib) * (NH * C) + h * C + k0 + kq];
    __syncthreads();
    As[ka + 0][ra] = a4.x; As[ka + 1][ra] = a4.y; As[ka + 2][ra] = a4.z; As[ka + 3][ra] = a4.w;
    Bs[kq + 0][ib] = b4.x; Bs[kq + 1][ib] = b4.y; Bs[kq + 2][ib] = b4.z; Bs[kq + 3][ib] = b4.w;
    __syncthreads();
#pragma unroll
    for (int kk = 0; kk < 16; ++kk) {
      float av[4], bw[4];
#pragma unroll
      for (int a = 0; a < 4; ++a) av[a] = As[kk][tm + a];
#pragma unroll
      for (int b = 0; b < 4; ++b) bw[b] = Bs[kk][tn + b];
#pragma unroll
      for (int a = 0; a < 4; ++a)
#pragma unroll
        for (int b = 0; b < 4; ++b) acc[a][b] += av[a] * bw[b];
    }
  }
#pragma unroll
  for (int a = 0; a < 4; ++a) {
    int c = h * DH + tm + a;
    float bb = bv[c];
    float4 o = {acc[a][0] + bb, acc[a][1] + bb, acc[a][2] + bb, acc[a][3] + bb};
    *(float4*)&outb[(size_t)c * n + i0 + tn] = o;
  }
}

// ---------- y[i][co] = sum_c wo[co][c] * outb[c][i] + bo[co] ----------
__global__ void k_ygemm(const float* __restrict__ outb, const float* __restrict__ wo,
                        const float* __restrict__ bo, float* __restrict__ y, int n) {
  __shared__ float As[16][64];  // As[kk][ii]
  __shared__ float Bs[16][68];  // Bs[kk][cc]
  int c0 = blockIdx.x * 64;
  int i0 = blockIdx.y * 64;
  int t = threadIdx.x;
  int tm = (t >> 4) << 2, tn = (t & 15) << 2;
  int kb = t >> 4, nb = (t & 15) << 2;
  int rb = t & 63, kq = (t >> 6) << 2;
  float acc[4][4] = {};
  for (int k0 = 0; k0 < C; k0 += 16) {
    float4 a4 = *(const float4*)&outb[(size_t)(k0 + kb) * n + i0 + nb];
    float4 b4 = *(const float4*)&wo[(c0 + rb) * C + k0 + kq];
    __syncthreads();
    *(float4*)&As[kb][nb] = a4;
    Bs[kq + 0][rb] = b4.x; Bs[kq + 1][rb] = b4.y; Bs[kq + 2][rb] = b4.z; Bs[kq + 3][rb] = b4.w;
    __syncthreads();
#pragma unroll
    for (int kk = 0; kk < 16; ++kk) {
      float av[4], bw[4];
#pragma unroll
      for (int a = 0; a < 4; ++a) av[a] = As[kk][tm + a];
#pragma unroll
      for (int b = 0; b < 4; ++b) bw[b] = Bs[kk][tn + b];
#pragma unroll
      for (int a = 0; a < 4; ++a)
#pragma unroll
        for (int b = 0; b < 4; ++b) acc[a][b] += av[a] * bw[b];
    }
  }
#pragma unroll
  for (int a = 0; a < 4; ++a) {
    float4 o;
    o.x = acc[a][0] + bo[c0 + tn + 0];
    o.y = acc[a][1] + bo[c0 + tn + 1];
    o.z = acc[a][2] + bo[c0 + tn + 2];
    o.w = acc[a][3] + bo[c0 + tn + 3];
    *(float4*)&y[(size_t)(i0 + tm + a) * C + c0 + tn] = o;
  }
}

// ---------- sig[i] = sigmoid(y[i][labels[i]]) ----------
__global__ void k_sig(const float* __restrict__ y, const int* __restrict__ labels,
                      float* __restrict__ sig, int n) {
  int i = blockIdx.x * 256 + threadIdx.x;
  if (i >= n) return;
  float v = y[(size_t)i * C + labels[i]];
  sig[i] = 1.0f / (1.0f + expf(-v));
}

}  // namespace

extern "C" void kernel_launch(void* const* d_in, const int* in_sizes, int n_in,
                              void* d_out, int out_size, void* d_ws, size_t ws_size,
                              hipStream_t stream) {
  (void)n_in; (void)out_size; (void)ws_size;
  const float* x = (const float*)d_in[0];
  const int* idx = (const int*)d_in[1];
  const int* labels = (const int*)d_in[2];
  const float* wq = (const float*)d_in[3];
  const float* bq = (const float*)d_in[4];
  const float* wk = (const float*)d_in[5];
  // bk (d_in[6]) cancels exactly in softmax (constant shift per (h,i)) — unused.
  const float* wv = (const float*)d_in[7];
  const float* bv = (const float*)d_in[8];
  const float* wo = (const float*)d_in[9];
  const float* bo = (const float*)d_in[10];
  const float* ow1 = (const float*)d_in[11];
  const float* ob1 = (const float*)d_in[12];
  const float* g1 = (const float*)d_in[13];
  const float* b1 = (const float*)d_in[14];
  const float* ow2 = (const float*)d_in[15];
  const float* ob2 = (const float*)d_in[16];
  const float* g2 = (const float*)d_in[17];
  const float* b2 = (const float*)d_in[18];
  const float* ow3 = (const float*)d_in[19];
  int n = in_sizes[1] / 2;  // 2048

  // workspace layout (floats)
  float* ws = (float*)d_ws;
  float* xt = ws;                          // HW*C        = 2,097,152
  float* q = xt + (size_t)HW * C;          // C*HW        = 2,097,152
  float* t1 = q + (size_t)C * HW;          // C*HW
  float* t2 = t1 + (size_t)C * HW;         // C*HW
  float* qsel = t2 + (size_t)C * HW;       // C*n         = 1,048,576
  float* qk2 = qsel + (size_t)C * n;       // n*NH*C      = 8,388,608
  float* pos = qk2 + (size_t)n * NH * C;   // n*G*K*2     =   147,456
  float* xs2 = pos + (size_t)n * G * K * 2;// n*K*C       = 9,437,184
  float* z2 = xs2 + (size_t)n * K * C;     // n*NH*C      = 8,388,608
  float* outb = z2 + (size_t)n * NH * C;   // C*n         = 1,048,576

  // output layout: y (n,C) | attn (NH,n,K) | xr_sel (n,G*K,C) | sig (n)
  float* out_f = (float*)d_out;
  float* y_out = out_f;
  float* attn_out = y_out + (size_t)n * C;
  float* xr_out = attn_out + (size_t)NH * n * K;
  float* sig_out = xr_out + (size_t)n * G * K * C;

  k_transpose<<<dim3(HW / 32, C / 32), dim3(32, 8), 0, stream>>>(x, xt);
  k_gemm_nn<<<dim3(HW / 64, C / 64), 256, 0, stream>>>(wq, x, bq, q, C, HW, C);
  k_qsel<<<dim3((n + 255) / 256, C), 256, 0, stream>>>(q, idx, qsel, n);
  k_qk<<<dim3(n / 64, C / 64, NH), 256, 0, stream>>>(qsel, wk, qk2, n);
  k_dwln<<<dim3(G * HDIM), 256, 0, stream>>>(q, ow1, ob1, g1, b1, t1);
  k_dwln<<<dim3(G * HDIM), 256, 0, stream>>>(t1, ow2, ob2, g2, b2, t2);
  k_offsets<<<dim3(n * G), 64, 0, stream>>>(t2, ow3, idx, pos, n);
  k_sample<<<dim3(n * G), 256, 0, stream>>>(xt, pos, xr_out, xs2, n);
  k_attn<<<dim3(n), 256, 0, stream>>>(qk2, xs2, attn_out, z2, n);
  k_outgemm<<<dim3(n / 64, NH), 256, 0, stream>>>(wv, z2, bv, outb, n);
  k_ygemm<<<dim3(C / 64, n / 64), 256, 0, stream>>>(outb, wo, bo, y_out, n);
  k_sig<<<dim3((n + 255) / 256), 256, 0, stream>>>(y_out, labels, sig_out, n);
}

// Round 2
// 424.761 us; speedup vs baseline: 1.3989x; 1.3989x over previous
//
#include <hip/hip_runtime.h>
#include <math.h>

namespace {

typedef unsigned short u16;
typedef __attribute__((ext_vector_type(8))) short bf16x8;
typedef __attribute__((ext_vector_type(4))) float f32x4;

constexpr int HDIM = 64;
constexpr int WDIM = 64;
constexpr int HW = HDIM * WDIM;   // 4096
constexpr int C = 512;
constexpr int G = 4;
constexpr int CG = 128;
constexpr int K = 9;
constexpr int NH = 8;
constexpr float SCALE = 0.125f;   // DH^-0.5

__device__ __forceinline__ u16 f2b(float f) {
  union { float f; unsigned int u; } v; v.f = f;
  unsigned int u = v.u;
  return (u16)((u + 0x7FFFu + ((u >> 16) & 1u)) >> 16);
}

// ---------- one-time weight converts: wq, wv, wo -> bf16 ----------
__global__ void k_convert3(const float* __restrict__ a, const float* __restrict__ b,
                           const float* __restrict__ c, u16* __restrict__ da,
                           u16* __restrict__ db, u16* __restrict__ dc) {
  int j = blockIdx.x * 256 + threadIdx.x;   // grid covers C*C
  da[j] = f2b(a[j]);
  db[j] = f2b(b[j]);
  dc[j] = f2b(c[j]);
}

// ---------- wkT[c'][hd] = bf16(wk[hd][c']) ----------
__global__ void k_wkT(const float* __restrict__ wk, u16* __restrict__ wkT) {
  __shared__ float tile[32][33];
  int r0 = blockIdx.x * 32;  // hd
  int c0 = blockIdx.y * 32;  // c'
  int tx = threadIdx.x, ty = threadIdx.y;
  for (int r = ty; r < 32; r += 8)
    tile[r][tx] = wk[(r0 + r) * C + c0 + tx];
  __syncthreads();
  for (int r = ty; r < 32; r += 8)
    wkT[(c0 + r) * C + r0 + tx] = f2b(tile[tx][r]);
}

// ---------- transpose x (C, HW) -> xt (HW, C) fp32 + xtb bf16 ----------
__global__ void k_transpose(const float* __restrict__ x, float* __restrict__ xt,
                            u16* __restrict__ xtb) {
  __shared__ float tile[32][33];
  int p0 = blockIdx.x * 32;
  int c0 = blockIdx.y * 32;
  int tx = threadIdx.x, ty = threadIdx.y;
  for (int r = ty; r < 32; r += 8)
    tile[r][tx] = x[(c0 + r) * HW + p0 + tx];
  __syncthreads();
  for (int r = ty; r < 32; r += 8) {
    float v = tile[tx][r];
    xt[(p0 + r) * C + c0 + tx] = v;
    xtb[(p0 + r) * C + c0 + tx] = f2b(v);
  }
}

// ---------- unified bf16 MFMA GEMM: D[m][n] = sum_k A[m][k] * BT[n][k] (+bias[n]) ----------
// A row-major K-contig (lda), BT row-major K-contig (ldb). Batched via blockIdx.z
// with element offsets. Block = 256 thr = 4 waves; block tile 64x64, wave 32x32.
template <bool OUT_BF16>
__global__ void __launch_bounds__(256)
k_gemm_mfma(const u16* __restrict__ A, int lda, int aOffZ,
            const u16* __restrict__ BT, int ldb, int bOffZ,
            const float* __restrict__ bias, int biasOffZ,
            void* __restrict__ Dp, int ldd, int dOffZ, int Kd) {
  int z = blockIdx.z;
  const u16* Ab = A + (size_t)z * aOffZ;
  const u16* Bb = BT + (size_t)z * bOffZ;
  int t = threadIdx.x;
  int wave = t >> 6, lane = t & 63;
  int wm = (wave >> 1) * 32, wn = (wave & 1) * 32;
  int bm = blockIdx.x * 64 + wm;
  int bn = blockIdx.y * 64 + wn;
  int row = lane & 15, quad = lane >> 4;
  f32x4 acc[2][2] = {};
  for (int k0 = 0; k0 < Kd; k0 += 32) {
    bf16x8 a[2], b[2];
#pragma unroll
    for (int mt = 0; mt < 2; ++mt)
      a[mt] = *(const bf16x8*)&Ab[(size_t)(bm + mt * 16 + row) * lda + k0 + quad * 8];
#pragma unroll
    for (int nt = 0; nt < 2; ++nt)
      b[nt] = *(const bf16x8*)&Bb[(size_t)(bn + nt * 16 + row) * ldb + k0 + quad * 8];
#pragma unroll
    for (int mt = 0; mt < 2; ++mt)
#pragma unroll
      for (int nt = 0; nt < 2; ++nt)
        acc[mt][nt] = __builtin_amdgcn_mfma_f32_16x16x32_bf16(a[mt], b[nt], acc[mt][nt], 0, 0, 0);
  }
#pragma unroll
  for (int nt = 0; nt < 2; ++nt) {
    int cc = bn + nt * 16 + row;   // D col = lane&15
    float bb = bias ? bias[(size_t)z * biasOffZ + cc] : 0.0f;
#pragma unroll
    for (int mt = 0; mt < 2; ++mt)
#pragma unroll
      for (int r = 0; r < 4; ++r) {
        int rr = bm + mt * 16 + quad * 4 + r;   // D row = quad*4+reg
        float v = acc[mt][nt][r] + bb;
        if (OUT_BF16)
          ((u16*)Dp)[(size_t)z * dOffZ + (size_t)rr * ldd + cc] = f2b(v);
        else
          ((float*)Dp)[(size_t)z * dOffZ + (size_t)rr * ldd + cc] = v;
      }
  }
}

// ---------- depthwise 3x3 conv + LN(128-ch group) + exact GELU, (p,c) layout ----------
__global__ void __launch_bounds__(512)
k_dwln2(const float* __restrict__ in, const float* __restrict__ w9,
        const float* __restrict__ wb, const float* __restrict__ lng,
        const float* __restrict__ lnb, float* __restrict__ outp) {
  int p = blockIdx.x;            // spatial position
  int h = p >> 6, w = p & 63;
  int t = threadIdx.x;           // channel c (0..511)
  int cg = t & 127;
  float acc = wb[cg];
#pragma unroll
  for (int dy = 0; dy < 3; ++dy) {
    int hh = h + dy - 1;
    if (hh < 0 || hh >= HDIM) continue;
#pragma unroll
    for (int dx = 0; dx < 3; ++dx) {
      int ww = w + dx - 1;
      if (ww < 0 || ww >= WDIM) continue;
      acc += w9[cg * 9 + dy * 3 + dx] * in[(hh * WDIM + ww) * C + t];
    }
  }
  float s = acc, s2 = acc * acc;
#pragma unroll
  for (int o = 32; o > 0; o >>= 1) {
    s += __shfl_xor(s, o, 64);
    s2 += __shfl_xor(s2, o, 64);
  }
  __shared__ float red[8][2];
  int wv = t >> 6;
  if ((t & 63) == 0) { red[wv][0] = s; red[wv][1] = s2; }
  __syncthreads();
  float S = red[wv][0] + red[wv ^ 1][0];
  float S2 = red[wv][1] + red[wv ^ 1][1];
  float mean = S * (1.0f / 128.0f);
  float var = S2 * (1.0f / 128.0f) - mean * mean;
  float xn = (acc - mean) * rsqrtf(var + 1e-5f) * lng[cg] + lnb[cg];
  outp[(size_t)p * C + t] = 0.5f * xn * (1.0f + erff(xn * 0.70710678f));
}

// ---------- offset projection + tanh + positions, one block per point ----------
__global__ void __launch_bounds__(128)
k_offsets2(const float* __restrict__ t2, const float* __restrict__ ow3,
           const int* __restrict__ idx, float* __restrict__ pos) {
  int i = blockIdx.x;
  int t = threadIdx.x;
  int iy = idx[2 * i], ix = idx[2 * i + 1];
  int p = iy * WDIM + ix;
  __shared__ float tl[512];
  __shared__ float ov[72];
#pragma unroll
  for (int j = 0; j < 4; ++j) tl[t + 128 * j] = t2[(size_t)p * C + t + 128 * j];
  __syncthreads();
  if (t < 72) {
    int g = t / 18, l = t % 18;
    float a = 0.0f;
#pragma unroll 4
    for (int j = 0; j < 128; ++j) a += ow3[l * CG + j] * tl[g * CG + j];
    ov[t] = a;
  }
  __syncthreads();
  if (t < 36) {
    int g = t / 9, l = t % 9;
    int dy = l / 3, dx = l % 3;
    int ryi = min(max(iy + dy - 1, 0), HDIM - 1);
    int rxi = min(max(ix + dx - 1, 0), WDIM - 1);
    float ry = (ryi + 0.5f) * (2.0f / HDIM) - 1.0f;
    float rx = (rxi + 0.5f) * (2.0f / WDIM) - 1.0f;
    float py = tanhf(ov[g * 18 + 2 * l]) * (2.0f / HDIM) + ry;
    float px = tanhf(ov[g * 18 + 2 * l + 1]) * (2.0f / WDIM) + rx;
    int o = ((i * G + g) * K + l) * 2;
    pos[o] = py;
    pos[o + 1] = px;
  }
}

// ---------- gather q_t at selected points -> qselb (n x C) bf16 ----------
__global__ void k_qsel2(const float* __restrict__ q_t, const int* __restrict__ idx,
                        u16* __restrict__ qselb) {
  int i = blockIdx.x;
  int t = threadIdx.x;  // 256
  int p = idx[2 * i] * WDIM + idx[2 * i + 1];
  qselb[(size_t)i * C + t] = f2b(q_t[(size_t)p * C + t]);
  qselb[(size_t)i * C + t + 256] = f2b(q_t[(size_t)p * C + t + 256]);
}

// ---------- bilinear sampler: writes xr_sel (all C) and xs_sel (own-group C) ----------
__global__ void k_sample(const float* __restrict__ xt, const float* __restrict__ pos,
                         float* __restrict__ xr, float* __restrict__ xs2, int n) {
  int i = blockIdx.x >> 2;
  int g = blockIdx.x & 3;
  int t = threadIdx.x;
#pragma unroll 1
  for (int kk = 0; kk < K; ++kk) {
    int o = ((i * G + g) * K + kk) * 2;
    float py = pos[o], px = pos[o + 1];
    float gx = (px + 1.0f) * 0.5f * (WDIM - 1);
    float gy = (py + 1.0f) * 0.5f * (HDIM - 1);
    float x0f = floorf(gx), y0f = floorf(gy);
    float wx1 = gx - x0f, wx0 = 1.0f - wx1;
    float wy1 = gy - y0f, wy0 = 1.0f - wy1;
    int x0 = (int)x0f, y0 = (int)y0f;
    int x1 = x0 + 1, y1 = y0 + 1;
    bool vx0 = (x0 >= 0) && (x0 < WDIM);
    bool vx1 = (x1 >= 0) && (x1 < WDIM);
    bool vy0 = (y0 >= 0) && (y0 < HDIM);
    bool vy1 = (y1 >= 0) && (y1 < HDIM);
    float w00 = (vy0 && vx0) ? wy0 * wx0 : 0.0f;
    float w01 = (vy0 && vx1) ? wy0 * wx1 : 0.0f;
    float w10 = (vy1 && vx0) ? wy1 * wx0 : 0.0f;
    float w11 = (vy1 && vx1) ? wy1 * wx1 : 0.0f;
    int x0c = min(max(x0, 0), WDIM - 1), x1c = min(max(x1, 0), WDIM - 1);
    int y0c = min(max(y0, 0), HDIM - 1), y1c = min(max(y1, 0), HDIM - 1);
    const float* p00 = xt + (y0c * WDIM + x0c) * C;
    const float* p01 = xt + (y0c * WDIM + x1c) * C;
    const float* p10 = xt + (y1c * WDIM + x0c) * C;
    const float* p11 = xt + (y1c * WDIM + x1c) * C;
    size_t rbase = ((size_t)i * (G * K) + g * K + kk) * C;
    size_t sbase = ((size_t)i * K + kk) * C;
    for (int c = t; c < C; c += 256) {
      float v = w00 * p00[c] + w01 * p01[c] + w10 * p10[c] + w11 * p11[c];
      xr[rbase + c] = v;
      if ((c >> 7) == g) xs2[sbase + c] = v;
    }
  }
}

// ---------- fused per-point attention: logits -> softmax -> z (bf16) ----------
__global__ void __launch_bounds__(256)
k_attn(const float* __restrict__ qk2, const float* __restrict__ xs2,
       float* __restrict__ attn_out, u16* __restrict__ z2b, int n) {
  int i = blockIdx.x;
  int t = threadIdx.x;
  __shared__ float qkl[NH * C];  // 4096
  __shared__ float xsl[K * C];   // 4608
  __shared__ float lg[NH][K];
  __shared__ float pr[NH][K];
  for (int j = t; j < NH * C; j += 256) qkl[j] = qk2[(size_t)i * (NH * C) + j];
  for (int j = t; j < K * C; j += 256) xsl[j] = xs2[(size_t)i * (K * C) + j];
  __syncthreads();
  int wave = t >> 6, lane = t & 63;
#pragma unroll
  for (int hh = 0; hh < 2; ++hh) {
    int h = wave * 2 + hh;
#pragma unroll 1
    for (int kk = 0; kk < K; ++kk) {
      float s = 0.0f;
#pragma unroll
      for (int m = 0; m < 8; ++m)
        s += qkl[h * C + lane + 64 * m] * xsl[kk * C + lane + 64 * m];
#pragma unroll
      for (int o = 32; o > 0; o >>= 1) s += __shfl_xor(s, o, 64);
      if (lane == 0) lg[h][kk] = s * SCALE;
    }
  }
  __syncthreads();
  if (t < NH) {
    float mx = -1e30f;
    for (int kk = 0; kk < K; ++kk) mx = fmaxf(mx, lg[t][kk]);
    float sm = 0.0f;
    float e[K];
    for (int kk = 0; kk < K; ++kk) { e[kk] = expf(lg[t][kk] - mx); sm += e[kk]; }
    float inv = 1.0f / sm;
    for (int kk = 0; kk < K; ++kk) {
      float p = e[kk] * inv;
      pr[t][kk] = p;
      attn_out[((size_t)t * n + i) * K + kk] = p;
    }
  }
  __syncthreads();
  for (int j = t; j < NH * C; j += 256) {
    int h = j >> 9;
    int cc = j & 511;
    float a = 0.0f;
#pragma unroll
    for (int kk = 0; kk < K; ++kk) a += pr[h][kk] * xsl[kk * C + cc];
    z2b[(size_t)i * (NH * C) + j] = f2b(a);
  }
}

// ---------- sig[i] = sigmoid(y[i][labels[i]]) ----------
__global__ void k_sig(const float* __restrict__ y, const int* __restrict__ labels,
                      float* __restrict__ sig, int n) {
  int i = blockIdx.x * 256 + threadIdx.x;
  if (i >= n) return;
  float v = y[(size_t)i * C + labels[i]];
  sig[i] = 1.0f / (1.0f + expf(-v));
}

}  // namespace

extern "C" void kernel_launch(void* const* d_in, const int* in_sizes, int n_in,
                              void* d_out, int out_size, void* d_ws, size_t ws_size,
                              hipStream_t stream) {
  (void)n_in; (void)out_size; (void)ws_size;
  const float* x = (const float*)d_in[0];
  const int* idx = (const int*)d_in[1];
  const int* labels = (const int*)d_in[2];
  const float* wq = (const float*)d_in[3];
  const float* bq = (const float*)d_in[4];
  const float* wk = (const float*)d_in[5];
  // bk (d_in[6]) cancels exactly in softmax — unused.
  const float* wv = (const float*)d_in[7];
  const float* bv = (const float*)d_in[8];
  const float* wo = (const float*)d_in[9];
  const float* bo = (const float*)d_in[10];
  const float* ow1 = (const float*)d_in[11];
  const float* ob1 = (const float*)d_in[12];
  const float* g1 = (const float*)d_in[13];
  const float* b1 = (const float*)d_in[14];
  const float* ow2 = (const float*)d_in[15];
  const float* ob2 = (const float*)d_in[16];
  const float* g2 = (const float*)d_in[17];
  const float* b2 = (const float*)d_in[18];
  const float* ow3 = (const float*)d_in[19];
  int n = in_sizes[1] / 2;  // 2048

  // ---- workspace carve-out (256B aligned) ----
  unsigned char* wp = (unsigned char*)d_ws;
  auto alloc = [&](size_t bytes) {
    unsigned char* p = wp;
    wp += (bytes + 255) & ~(size_t)255;
    return p;
  };
  float* xt = (float*)alloc((size_t)HW * C * 4);
  u16* xtb = (u16*)alloc((size_t)HW * C * 2);
  u16* wqb = (u16*)alloc((size_t)C * C * 2);
  u16* wvb = (u16*)alloc((size_t)C * C * 2);
  u16* wob = (u16*)alloc((size_t)C * C * 2);
  u16* wkT = (u16*)alloc((size_t)C * C * 2);
  float* q_t = (float*)alloc((size_t)HW * C * 4);
  float* t1 = (float*)alloc((size_t)HW * C * 4);
  float* t2 = (float*)alloc((size_t)HW * C * 4);
  u16* qselb = (u16*)alloc((size_t)n * C * 2);
  float* qk2 = (float*)alloc((size_t)n * NH * C * 4);
  float* pos = (float*)alloc((size_t)n * G * K * 2 * 4);
  float* xs2 = (float*)alloc((size_t)n * K * C * 4);
  u16* z2b = (u16*)alloc((size_t)n * NH * C * 2);
  u16* outb = (u16*)alloc((size_t)n * C * 2);

  // output layout: y (n,C) | attn (NH,n,K) | xr_sel (n,G*K,C) | sig (n)
  float* out_f = (float*)d_out;
  float* y_out = out_f;
  float* attn_out = y_out + (size_t)n * C;
  float* xr_out = attn_out + (size_t)NH * n * K;
  float* sig_out = xr_out + (size_t)n * G * K * C;

  // one-time converts
  k_convert3<<<dim3(C * C / 256), 256, 0, stream>>>(wq, wv, wo, wqb, wvb, wob);
  k_wkT<<<dim3(C / 32, C / 32), dim3(32, 8), 0, stream>>>(wk, wkT);
  k_transpose<<<dim3(HW / 32, C / 32), dim3(32, 8), 0, stream>>>(x, xt, xtb);

  // GEMM1: q_t[p][c] = sum_k xtb[p][k] * wqb[c][k] + bq[c]   (fp32 out)
  k_gemm_mfma<false><<<dim3(HW / 64, C / 64, 1), 256, 0, stream>>>(
      xtb, C, 0, wqb, C, 0, bq, 0, q_t, C, 0, C);

  k_dwln2<<<dim3(HW), 512, 0, stream>>>(q_t, ow1, ob1, g1, b1, t1);
  k_dwln2<<<dim3(HW), 512, 0, stream>>>(t1, ow2, ob2, g2, b2, t2);
  k_offsets2<<<dim3(n), 128, 0, stream>>>(t2, ow3, idx, pos);
  k_qsel2<<<dim3(n), 256, 0, stream>>>(q_t, idx, qselb);

  // GEMM2 (per head): qk2[i][h*512+c'] = sum_d qselb[i][h*64+d] * wkT[c'][h*64+d]
  k_gemm_mfma<false><<<dim3(n / 64, C / 64, NH), 256, 0, stream>>>(
      qselb, C, 64, wkT, C, 64, nullptr, 0, qk2, NH * C, C, 64);

  k_sample<<<dim3(n * G), 256, 0, stream>>>(xt, pos, xr_out, xs2, n);
  k_attn<<<dim3(n), 256, 0, stream>>>(qk2, xs2, attn_out, z2b, n);

  // GEMM3 (per head): outb[i][h*64+d] = sum_c' z2b[i][h*512+c'] * wvb[h*64+d][c'] + bv  (bf16 out)
  k_gemm_mfma<true><<<dim3(n / 64, 1, NH), 256, 0, stream>>>(
      z2b, NH * C, C, wvb, C, 64 * C, bv, 64, outb, C, 64, C);

  // GEMM4: y[i][co] = sum_c outb[i][c] * wob[co][c] + bo[co]  (fp32 out)
  k_gemm_mfma<false><<<dim3(n / 64, C / 64, 1), 256, 0, stream>>>(
      outb, C, 0, wob, C, 0, bo, 0, y_out, C, 0, C);

  k_sig<<<dim3((n + 255) / 256), 256, 0, stream>>>(y_out, labels, sig_out, n);
}

// Round 4
// 346.224 us; speedup vs baseline: 1.7162x; 1.2268x over previous
//
#include <hip/hip_runtime.h>
#include <math.h>

namespace {

typedef unsigned short u16;
typedef unsigned int u32;
typedef __attribute__((ext_vector_type(8))) short bf16x8;
typedef __attribute__((ext_vector_type(4))) float f32x4;
typedef __attribute__((ext_vector_type(2))) float f32x2;

constexpr int HDIM = 64;
constexpr int WDIM = 64;
constexpr int HW = HDIM * WDIM;   // 4096
constexpr int C = 512;
constexpr int G = 4;
constexpr int CG = 128;
constexpr int K = 9;
constexpr int NH = 8;
constexpr float SCALE = 0.125f;   // DH^-0.5

__device__ __forceinline__ u16 f2b(float f) {
  union { float f; u32 u; } v; v.f = f;
  u32 u = v.u;
  return (u16)((u + 0x7FFFu + ((u >> 16) & 1u)) >> 16);
}
__device__ __forceinline__ float b2f(u16 b) {
  union { u32 u; float f; } v; v.u = ((u32)b) << 16;
  return v.f;
}

// ---------- one-time weight converts: wq, wv, wo -> bf16 ----------
__global__ void k_convert3(const float* __restrict__ a, const float* __restrict__ b,
                           const float* __restrict__ c, u16* __restrict__ da,
                           u16* __restrict__ db, u16* __restrict__ dc) {
  int j = blockIdx.x * 256 + threadIdx.x;
  da[j] = f2b(a[j]);
  db[j] = f2b(b[j]);
  dc[j] = f2b(c[j]);
}

// ---------- wkT[c'][hd] = bf16(wk[hd][c']) ----------
__global__ void k_wkT(const float* __restrict__ wk, u16* __restrict__ wkT) {
  __shared__ float tile[32][33];
  int r0 = blockIdx.x * 32;
  int c0 = blockIdx.y * 32;
  int tx = threadIdx.x, ty = threadIdx.y;
  for (int r = ty; r < 32; r += 8)
    tile[r][tx] = wk[(r0 + r) * C + c0 + tx];
  __syncthreads();
  for (int r = ty; r < 32; r += 8)
    wkT[(c0 + r) * C + r0 + tx] = f2b(tile[tx][r]);
}

// ---------- transpose x (C, HW) -> xtb (HW, C) bf16 ----------
__global__ void k_transpose(const float* __restrict__ x, u16* __restrict__ xtb) {
  __shared__ float tile[32][33];
  int p0 = blockIdx.x * 32;
  int c0 = blockIdx.y * 32;
  int tx = threadIdx.x, ty = threadIdx.y;
  for (int r = ty; r < 32; r += 8)
    tile[r][tx] = x[(c0 + r) * HW + p0 + tx];
  __syncthreads();
  for (int r = ty; r < 32; r += 8)
    xtb[(p0 + r) * C + c0 + tx] = f2b(tile[tx][r]);
}

// ---------- unified bf16 MFMA GEMM: D[m][n] = sum_k A[m][k] * BT[n][k] (+bias[n]) ----------
template <bool OUT_BF16>
__global__ void __launch_bounds__(256)
k_gemm_mfma(const u16* __restrict__ A, int lda, int aOffZ,
            const u16* __restrict__ BT, int ldb, int bOffZ,
            const float* __restrict__ bias, int biasOffZ,
            void* __restrict__ Dp, int ldd, int dOffZ, int Kd) {
  int z = blockIdx.z;
  const u16* Ab = A + (size_t)z * aOffZ;
  const u16* Bb = BT + (size_t)z * bOffZ;
  int t = threadIdx.x;
  int wave = t >> 6, lane = t & 63;
  int wm = (wave >> 1) * 32, wn = (wave & 1) * 32;
  int bm = blockIdx.x * 64 + wm;
  int bn = blockIdx.y * 64 + wn;
  int row = lane & 15, quad = lane >> 4;
  f32x4 acc[2][2] = {};
  for (int k0 = 0; k0 < Kd; k0 += 32) {
    bf16x8 a[2], b[2];
#pragma unroll
    for (int mt = 0; mt < 2; ++mt)
      a[mt] = *(const bf16x8*)&Ab[(size_t)(bm + mt * 16 + row) * lda + k0 + quad * 8];
#pragma unroll
    for (int nt = 0; nt < 2; ++nt)
      b[nt] = *(const bf16x8*)&Bb[(size_t)(bn + nt * 16 + row) * ldb + k0 + quad * 8];
#pragma unroll
    for (int mt = 0; mt < 2; ++mt)
#pragma unroll
      for (int nt = 0; nt < 2; ++nt)
        acc[mt][nt] = __builtin_amdgcn_mfma_f32_16x16x32_bf16(a[mt], b[nt], acc[mt][nt], 0, 0, 0);
  }
#pragma unroll
  for (int nt = 0; nt < 2; ++nt) {
    int cc = bn + nt * 16 + row;
    float bb = bias ? bias[(size_t)z * biasOffZ + cc] : 0.0f;
#pragma unroll
    for (int mt = 0; mt < 2; ++mt)
#pragma unroll
      for (int r = 0; r < 4; ++r) {
        int rr = bm + mt * 16 + quad * 4 + r;
        float v = acc[mt][nt][r] + bb;
        if (OUT_BF16)
          ((u16*)Dp)[(size_t)z * dOffZ + (size_t)rr * ldd + cc] = f2b(v);
        else
          ((float*)Dp)[(size_t)z * dOffZ + (size_t)rr * ldd + cc] = v;
      }
  }
}

// ---------- depthwise 3x3 conv + LN(128-ch) + exact GELU, (p,c) layout, bf16 io ----------
__global__ void __launch_bounds__(512)
k_dwln2(const u16* __restrict__ in, const float* __restrict__ w9,
        const float* __restrict__ wb, const float* __restrict__ lng,
        const float* __restrict__ lnb, u16* __restrict__ outp) {
  int p = blockIdx.x;
  int h = p >> 6, w = p & 63;
  int t = threadIdx.x;
  int cg = t & 127;
  float acc = wb[cg];
#pragma unroll
  for (int dy = 0; dy < 3; ++dy) {
    int hh = h + dy - 1;
    if (hh < 0 || hh >= HDIM) continue;
#pragma unroll
    for (int dx = 0; dx < 3; ++dx) {
      int ww = w + dx - 1;
      if (ww < 0 || ww >= WDIM) continue;
      acc += w9[cg * 9 + dy * 3 + dx] * b2f(in[(hh * WDIM + ww) * C + t]);
    }
  }
  float s = acc, s2 = acc * acc;
#pragma unroll
  for (int o = 32; o > 0; o >>= 1) {
    s += __shfl_xor(s, o, 64);
    s2 += __shfl_xor(s2, o, 64);
  }
  __shared__ float red[8][2];
  int wv = t >> 6;
  if ((t & 63) == 0) { red[wv][0] = s; red[wv][1] = s2; }
  __syncthreads();
  float S = red[wv][0] + red[wv ^ 1][0];
  float S2 = red[wv][1] + red[wv ^ 1][1];
  float mean = S * (1.0f / 128.0f);
  float var = S2 * (1.0f / 128.0f) - mean * mean;
  float xn = (acc - mean) * rsqrtf(var + 1e-5f) * lng[cg] + lnb[cg];
  outp[(size_t)p * C + t] = f2b(0.5f * xn * (1.0f + erff(xn * 0.70710678f)));
}

// ---------- offset projection + tanh + positions ----------
__global__ void __launch_bounds__(128)
k_offsets2(const u16* __restrict__ t2, const float* __restrict__ ow3,
           const int* __restrict__ idx, float* __restrict__ pos) {
  int i = blockIdx.x;
  int t = threadIdx.x;
  int iy = idx[2 * i], ix = idx[2 * i + 1];
  int p = iy * WDIM + ix;
  __shared__ float tl[512];
  __shared__ float ov[72];
#pragma unroll
  for (int j = 0; j < 4; ++j) tl[t + 128 * j] = b2f(t2[(size_t)p * C + t + 128 * j]);
  __syncthreads();
  if (t < 72) {
    int g = t / 18, l = t % 18;
    float a = 0.0f;
#pragma unroll 4
    for (int j = 0; j < 128; ++j) a += ow3[l * CG + j] * tl[g * CG + j];
    ov[t] = a;
  }
  __syncthreads();
  if (t < 36) {
    int g = t / 9, l = t % 9;
    int dy = l / 3, dx = l % 3;
    int ryi = min(max(iy + dy - 1, 0), HDIM - 1);
    int rxi = min(max(ix + dx - 1, 0), WDIM - 1);
    float ry = (ryi + 0.5f) * (2.0f / HDIM) - 1.0f;
    float rx = (rxi + 0.5f) * (2.0f / WDIM) - 1.0f;
    float py = tanhf(ov[g * 18 + 2 * l]) * (2.0f / HDIM) + ry;
    float px = tanhf(ov[g * 18 + 2 * l + 1]) * (2.0f / WDIM) + rx;
    int o = ((i * G + g) * K + l) * 2;
    pos[o] = py;
    pos[o + 1] = px;
  }
}

// ---------- gather q_t (bf16) at selected points -> qselb ----------
__global__ void k_qsel2(const u16* __restrict__ q_tb, const int* __restrict__ idx,
                        u16* __restrict__ qselb) {
  int i = blockIdx.x;
  int t = threadIdx.x;  // 256
  int p = idx[2 * i] * WDIM + idx[2 * i + 1];
  ((u32*)qselb)[(size_t)i * 256 + t] = ((const u32*)q_tb)[(size_t)p * 256 + t];
}

// ---------- bilinear weights helper ----------
struct Bilin {
  const u16 *r00, *r01, *r10, *r11;
  float w00, w01, w10, w11;
};
__device__ __forceinline__ Bilin bilin(const u16* xtb, float py, float px, int coff) {
  float gx = (px + 1.0f) * 0.5f * (WDIM - 1);
  float gy = (py + 1.0f) * 0.5f * (HDIM - 1);
  float x0f = floorf(gx), y0f = floorf(gy);
  float wx1 = gx - x0f, wx0 = 1.0f - wx1;
  float wy1 = gy - y0f, wy0 = 1.0f - wy1;
  int x0 = (int)x0f, y0 = (int)y0f;
  int x1 = x0 + 1, y1 = y0 + 1;
  bool vx0 = (x0 >= 0) && (x0 < WDIM);
  bool vx1 = (x1 >= 0) && (x1 < WDIM);
  bool vy0 = (y0 >= 0) && (y0 < HDIM);
  bool vy1 = (y1 >= 0) && (y1 < HDIM);
  Bilin bl;
  bl.w00 = (vy0 && vx0) ? wy0 * wx0 : 0.0f;
  bl.w01 = (vy0 && vx1) ? wy0 * wx1 : 0.0f;
  bl.w10 = (vy1 && vx0) ? wy1 * wx0 : 0.0f;
  bl.w11 = (vy1 && vx1) ? wy1 * wx1 : 0.0f;
  int x0c = min(max(x0, 0), WDIM - 1), x1c = min(max(x1, 0), WDIM - 1);
  int y0c = min(max(y0, 0), HDIM - 1), y1c = min(max(y1, 0), HDIM - 1);
  bl.r00 = xtb + (y0c * WDIM + x0c) * C + coff;
  bl.r01 = xtb + (y0c * WDIM + x1c) * C + coff;
  bl.r10 = xtb + (y1c * WDIM + x0c) * C + coff;
  bl.r11 = xtb + (y1c * WDIM + x1c) * C + coff;
  return bl;
}

// ---------- bilinear sampler: writes xr_sel only (bf16 source, fp32 out) ----------
__global__ void __launch_bounds__(256)
k_sample2(const u16* __restrict__ xtb, const float* __restrict__ pos,
          float* __restrict__ xr) {
  int i = blockIdx.x >> 2;
  int g = blockIdx.x & 3;
  int t = threadIdx.x;
  int c2 = t * 2;
#pragma unroll 1
  for (int kk = 0; kk < K; ++kk) {
    int o = ((i * G + g) * K + kk) * 2;
    Bilin bl = bilin(xtb, pos[o], pos[o + 1], 0);
    u32 a00 = *(const u32*)&bl.r00[c2];
    u32 a01 = *(const u32*)&bl.r01[c2];
    u32 a10 = *(const u32*)&bl.r10[c2];
    u32 a11 = *(const u32*)&bl.r11[c2];
    float v0 = bl.w00 * b2f((u16)a00) + bl.w01 * b2f((u16)a01) +
               bl.w10 * b2f((u16)a10) + bl.w11 * b2f((u16)a11);
    float v1 = bl.w00 * b2f((u16)(a00 >> 16)) + bl.w01 * b2f((u16)(a01 >> 16)) +
               bl.w10 * b2f((u16)(a10 >> 16)) + bl.w11 * b2f((u16)(a11 >> 16));
    f32x2 ov = {v0, v1};
    size_t rbase = ((size_t)i * (G * K) + g * K + kk) * C;
    __builtin_nontemporal_store(ov, (f32x2*)&xr[rbase + c2]);
  }
}

// ---------- fused attention: in-kernel gather + MFMA logits + softmax + z ----------
__global__ void __launch_bounds__(256)
k_attn2(const u16* __restrict__ qk2b, const u16* __restrict__ xtb,
        const float* __restrict__ pos, float* __restrict__ attn_out,
        u16* __restrict__ z2b, int n) {
  constexpr int LD = 520;  // row stride (u16) -> 1040 B: 2-way bank aliasing only
  int i = blockIdx.x;
  int t = threadIdx.x;
  __shared__ alignas(16) u16 qkl[16 * LD];
  __shared__ alignas(16) u16 xsl[16 * LD];
  __shared__ float posl[72];
  __shared__ float lg[NH][K];
  __shared__ float pr[NH][K];
  const u16* qsrc = qk2b + (size_t)i * (NH * C);
  for (int j = t; j < NH * C; j += 256) qkl[(j >> 9) * LD + (j & 511)] = qsrc[j];
  if (t < 72) posl[t] = pos[(size_t)i * 72 + t];
  __syncthreads();
  int wave = t >> 6, lane = t & 63;
  // gather: wave = group g, 9 taps each; lane covers 2 channels of the 128-ch group
  {
    int g = wave;
#pragma unroll 1
    for (int kk = 0; kk < K; ++kk) {
      Bilin bl = bilin(xtb, posl[(g * K + kk) * 2], posl[(g * K + kk) * 2 + 1], g * CG);
      int c2 = lane * 2;
      u32 a00 = *(const u32*)&bl.r00[c2];
      u32 a01 = *(const u32*)&bl.r01[c2];
      u32 a10 = *(const u32*)&bl.r10[c2];
      u32 a11 = *(const u32*)&bl.r11[c2];
      float v0 = bl.w00 * b2f((u16)a00) + bl.w01 * b2f((u16)a01) +
                 bl.w10 * b2f((u16)a10) + bl.w11 * b2f((u16)a11);
      float v1 = bl.w00 * b2f((u16)(a00 >> 16)) + bl.w01 * b2f((u16)(a01 >> 16)) +
                 bl.w10 * b2f((u16)(a10 >> 16)) + bl.w11 * b2f((u16)(a11 >> 16));
      *(u32*)&xsl[kk * LD + g * CG + c2] = ((u32)f2b(v1) << 16) | f2b(v0);
    }
  }
  __syncthreads();
  // logits: one wave, one 16x16 MFMA tile over K=512 (rows>=8 / cols>=9 garbage, unused)
  if (wave == 0) {
    int row = lane & 15, quad = lane >> 4;
    f32x4 acc = {};
#pragma unroll 4
    for (int k0 = 0; k0 < C; k0 += 32) {
      bf16x8 a = *(const bf16x8*)&qkl[row * LD + k0 + quad * 8];
      bf16x8 b = *(const bf16x8*)&xsl[row * LD + k0 + quad * 8];
      acc = __builtin_amdgcn_mfma_f32_16x16x32_bf16(a, b, acc, 0, 0, 0);
    }
    if (row < K && quad < 2) {
#pragma unroll
      for (int r = 0; r < 4; ++r) lg[quad * 4 + r][row] = acc[r] * SCALE;
    }
  }
  __syncthreads();
  if (t < NH) {
    float mx = -1e30f;
    for (int kk = 0; kk < K; ++kk) mx = fmaxf(mx, lg[t][kk]);
    float sm = 0.0f;
    float e[K];
    for (int kk = 0; kk < K; ++kk) { e[kk] = expf(lg[t][kk] - mx); sm += e[kk]; }
    float inv = 1.0f / sm;
    for (int kk = 0; kk < K; ++kk) {
      float p = e[kk] * inv;
      pr[t][kk] = p;
      attn_out[((size_t)t * n + i) * K + kk] = p;
    }
  }
  __syncthreads();
  for (int j = t; j < NH * C; j += 256) {
    int h = j >> 9;
    int cc = j & 511;
    float a = 0.0f;
#pragma unroll
    for (int kk = 0; kk < K; ++kk) a += pr[h][kk] * b2f(xsl[kk * LD + cc]);
    z2b[(size_t)i * (NH * C) + j] = f2b(a);
  }
}

// ---------- sig[i] = sigmoid(y[i][labels[i]]) ----------
__global__ void k_sig(const float* __restrict__ y, const int* __restrict__ labels,
                      float* __restrict__ sig, int n) {
  int i = blockIdx.x * 256 + threadIdx.x;
  if (i >= n) return;
  float v = y[(size_t)i * C + labels[i]];
  sig[i] = 1.0f / (1.0f + expf(-v));
}

}  // namespace

extern "C" void kernel_launch(void* const* d_in, const int* in_sizes, int n_in,
                              void* d_out, int out_size, void* d_ws, size_t ws_size,
                              hipStream_t stream) {
  (void)n_in; (void)out_size; (void)ws_size;
  const float* x = (const float*)d_in[0];
  const int* idx = (const int*)d_in[1];
  const int* labels = (const int*)d_in[2];
  const float* wq = (const float*)d_in[3];
  const float* bq = (const float*)d_in[4];
  const float* wk = (const float*)d_in[5];
  // bk (d_in[6]) cancels exactly in softmax — unused.
  const float* wv = (const float*)d_in[7];
  const float* bv = (const float*)d_in[8];
  const float* wo = (const float*)d_in[9];
  const float* bo = (const float*)d_in[10];
  const float* ow1 = (const float*)d_in[11];
  const float* ob1 = (const float*)d_in[12];
  const float* g1 = (const float*)d_in[13];
  const float* b1 = (const float*)d_in[14];
  const float* ow2 = (const float*)d_in[15];
  const float* ob2 = (const float*)d_in[16];
  const float* g2 = (const float*)d_in[17];
  const float* b2 = (const float*)d_in[18];
  const float* ow3 = (const float*)d_in[19];
  int n = in_sizes[1] / 2;  // 2048

  unsigned char* wp = (unsigned char*)d_ws;
  auto alloc = [&](size_t bytes) {
    unsigned char* p = wp;
    wp += (bytes + 255) & ~(size_t)255;
    return p;
  };
  u16* xtb = (u16*)alloc((size_t)HW * C * 2);
  u16* wqb = (u16*)alloc((size_t)C * C * 2);
  u16* wvb = (u16*)alloc((size_t)C * C * 2);
  u16* wob = (u16*)alloc((size_t)C * C * 2);
  u16* wkT = (u16*)alloc((size_t)C * C * 2);
  u16* q_tb = (u16*)alloc((size_t)HW * C * 2);
  u16* t1b = (u16*)alloc((size_t)HW * C * 2);
  u16* t2b = (u16*)alloc((size_t)HW * C * 2);
  u16* qselb = (u16*)alloc((size_t)n * C * 2);
  u16* qk2b = (u16*)alloc((size_t)n * NH * C * 2);
  float* pos = (float*)alloc((size_t)n * G * K * 2 * 4);
  u16* z2b = (u16*)alloc((size_t)n * NH * C * 2);
  u16* outb = (u16*)alloc((size_t)n * C * 2);

  // output layout: y (n,C) | attn (NH,n,K) | xr_sel (n,G*K,C) | sig (n)
  float* out_f = (float*)d_out;
  float* y_out = out_f;
  float* attn_out = y_out + (size_t)n * C;
  float* xr_out = attn_out + (size_t)NH * n * K;
  float* sig_out = xr_out + (size_t)n * G * K * C;

  k_convert3<<<dim3(C * C / 256), 256, 0, stream>>>(wq, wv, wo, wqb, wvb, wob);
  k_wkT<<<dim3(C / 32, C / 32), dim3(32, 8), 0, stream>>>(wk, wkT);
  k_transpose<<<dim3(HW / 32, C / 32), dim3(32, 8), 0, stream>>>(x, xtb);

  // GEMM1: q_tb[p][c] = sum_k xtb[p][k] * wqb[c][k] + bq[c]  (bf16 out)
  k_gemm_mfma<true><<<dim3(HW / 64, C / 64, 1), 256, 0, stream>>>(
      xtb, C, 0, wqb, C, 0, bq, 0, q_tb, C, 0, C);

  k_dwln2<<<dim3(HW), 512, 0, stream>>>(q_tb, ow1, ob1, g1, b1, t1b);
  k_dwln2<<<dim3(HW), 512, 0, stream>>>(t1b, ow2, ob2, g2, b2, t2b);
  k_offsets2<<<dim3(n), 128, 0, stream>>>(t2b, ow3, idx, pos);
  k_qsel2<<<dim3(n), 256, 0, stream>>>(q_tb, idx, qselb);

  // GEMM2 (per head): qk2b[i][h*512+c'] = sum_d qselb[i][h*64+d] * wkT[c'][h*64+d]
  k_gemm_mfma<true><<<dim3(n / 64, C / 64, NH), 256, 0, stream>>>(
      qselb, C, 64, wkT, C, 64, nullptr, 0, qk2b, NH * C, C, 64);

  k_sample2<<<dim3(n * G), 256, 0, stream>>>(xtb, pos, xr_out);
  k_attn2<<<dim3(n), 256, 0, stream>>>(qk2b, xtb, pos, attn_out, z2b, n);

  // GEMM3 (per head): outb[i][h*64+d] = sum_c' z2b[i][h*512+c'] * wvb[h*64+d][c'] + bv
  k_gemm_mfma<true><<<dim3(n / 64, 1, NH), 256, 0, stream>>>(
      z2b, NH * C, C, wvb, C, 64 * C, bv, 64, outb, C, 64, C);

  // GEMM4: y[i][co] = sum_c outb[i][c] * wob[co][c] + bo[co]  (fp32 out)
  k_gemm_mfma<false><<<dim3(n / 64, C / 64, 1), 256, 0, stream>>>(
      outb, C, 0, wob, C, 0, bo, 0, y_out, C, 0, C);

  k_sig<<<dim3((n + 255) / 256), 256, 0, stream>>>(y_out, labels, sig_out, n);
}